// Round 10
// baseline (796.289 us; speedup 1.0000x reference)
//
#include <hip/hip_runtime.h>

typedef __attribute__((ext_vector_type(8))) short short8;
typedef __attribute__((ext_vector_type(4))) float f32x4;

#define N_NODES 100000
#define N_EDGES 1600000
#define IN_F 128
#define OUT_ALL 64   // HEADS*OUT_F
#define HEADS 4
#define OUT_F 16
#define NTILES (N_NODES / 16)          // 6250
#define BIN_BLOCKS 512
#define EPB (N_EDGES / BIN_BLOCKS)     // 3125 edges per bin block
#define PROJ_BLOCKS 1536
#define TOTAL_BLOCKS (BIN_BLOCKS + PROJ_BLOCKS)
#define SLICE_SHIFT 8
#define SLICE_NODES 256
#define NSLICES ((N_NODES + SLICE_NODES - 1) / SLICE_NODES)   // 391
#define SEG_CAP 4608                   // avg 4096 + 8 sigma

static __device__ __forceinline__ ushort f2bf(float f) {
    unsigned u = __float_as_uint(f);
    return (ushort)((u + 0x7FFF + ((u >> 16) & 1)) >> 16);   // RN, no NaN inputs
}
static __device__ __forceinline__ float bf2f(ushort b) {
    return __uint_as_float(((unsigned)b) << 16);
}
static __device__ __forceinline__ short8 pack_bf16x8(float4 f0, float4 f1) {
    union { unsigned u[4]; short8 s; } r;
    asm("v_cvt_pk_bf16_f32 %0, %1, %2" : "=v"(r.u[0]) : "v"(f0.x), "v"(f0.y));
    asm("v_cvt_pk_bf16_f32 %0, %1, %2" : "=v"(r.u[1]) : "v"(f0.z), "v"(f0.w));
    asm("v_cvt_pk_bf16_f32 %0, %1, %2" : "=v"(r.u[2]) : "v"(f1.x), "v"(f1.y));
    asm("v_cvt_pk_bf16_f32 %0, %1, %2" : "=v"(r.u[3]) : "v"(f1.z), "v"(f1.w));
    return r.s;
}

// ---- Kernel 1: fused MFMA projection + slice-binning of edges ------------
// Bin role (blocks 0..511): stage 3125 edges in LDS, count per 256-node
// dst-slice with LDS atomics, ONE global atomicAdd per (block,slice)
// (~197K atomics total vs 1.6M -> the R7-measured coherence tax shrinks 8x),
// then flush each bin as a dense ~64B run into the slice's contiguous
// segment (block-exclusive bytes, no RFO sharing).
// Proj role (blocks 512..2047): unchanged R6 MFMA projection.
__global__ __launch_bounds__(256) void proj_bin_kernel(
    const float* __restrict__ x, const float* __restrict__ W,
    const float* __restrict__ att_i, const float* __restrict__ att_j,
    const int* __restrict__ ei,
    ushort* __restrict__ hb, float* __restrict__ ai, float* __restrict__ aj,
    int* __restrict__ scursor, int2* __restrict__ seg)
{
    __shared__ int2 est[EPB];                 // 25.0 KB
    __shared__ int  cnt[NSLICES];             // 1.6 KB
    __shared__ int  gbase[NSLICES];           // 1.6 KB
    __shared__ int  run[NSLICES];             // 1.6 KB

    if (blockIdx.x < BIN_BLOCKS) {
        int base = blockIdx.x * EPB;
        for (int i = threadIdx.x; i < EPB; i += 256) {
            int2 e;
            e.x = ei[base + i];               // src
            e.y = ei[N_EDGES + base + i];     // dst
            est[i] = e;
        }
        for (int s = threadIdx.x; s < NSLICES; s += 256) { cnt[s] = 0; run[s] = 0; }
        __syncthreads();
        for (int i = threadIdx.x; i < EPB; i += 256)
            atomicAdd(&cnt[est[i].y >> SLICE_SHIFT], 1);
        __syncthreads();
        for (int s = threadIdx.x; s < NSLICES; s += 256) {
            int c = cnt[s];
            gbase[s] = c ? atomicAdd(&scursor[s], c) : 0;
        }
        __syncthreads();
        for (int i = threadIdx.x; i < EPB; i += 256) {
            int2 e = est[i];
            int s = e.y >> SLICE_SHIFT;
            int p = gbase[s] + atomicAdd(&run[s], 1);
            if (p < SEG_CAP) seg[(size_t)s * SEG_CAP + p] = e;
        }
        return;
    }

    int bproj = blockIdx.x - BIN_BLOCKS;       // 0..1535
    const int nproj = PROJ_BLOCKS;

    int w   = threadIdx.x >> 6;    // wave id == head == 16-col n-tile
    int l   = threadIdx.x & 63;
    int col = l & 15;
    int kg  = l >> 4;              // k-group 0..3 (8 k each)

    short8 bw[4];
    #pragma unroll
    for (int m = 0; m < 4; ++m) {
        const float* wp = W + (size_t)(w * 16 + col) * IN_F + m * 32 + kg * 8;
        float4 f0 = *(const float4*)wp;
        float4 f1 = *(const float4*)(wp + 4);
        bw[m] = pack_bf16x8(f0, f1);
    }
    float atv_i = att_i[w * OUT_F + col];
    float atv_j = att_j[w * OUT_F + col];

    for (int t = bproj; t < NTILES; t += nproj) {
        int nodeBase = t * 16;
        const float* xp = x + (size_t)(nodeBase + col) * IN_F + kg * 8;
        short8 a[4];
        #pragma unroll
        for (int m = 0; m < 4; ++m) {
            float4 f0 = *(const float4*)(xp + m * 32);
            float4 f1 = *(const float4*)(xp + m * 32 + 4);
            a[m] = pack_bf16x8(f0, f1);
        }
        f32x4 acc = {0.f, 0.f, 0.f, 0.f};
        #pragma unroll
        for (int m = 0; m < 4; ++m)
            acc = __builtin_amdgcn_mfma_f32_16x16x32_bf16(a[m], bw[m], acc, 0, 0, 0);

        #pragma unroll
        for (int r = 0; r < 4; ++r)
            hb[(size_t)(nodeBase + kg * 4 + r) * OUT_ALL + w * 16 + col] = f2bf(acc[r]);

        float pi0 = acc[0] * atv_i, pi1 = acc[1] * atv_i,
              pi2 = acc[2] * atv_i, pi3 = acc[3] * atv_i;
        float pj0 = acc[0] * atv_j, pj1 = acc[1] * atv_j,
              pj2 = acc[2] * atv_j, pj3 = acc[3] * atv_j;
        #pragma unroll
        for (int d = 1; d < 16; d <<= 1) {
            pi0 += __shfl_xor(pi0, d, 64); pi1 += __shfl_xor(pi1, d, 64);
            pi2 += __shfl_xor(pi2, d, 64); pi3 += __shfl_xor(pi3, d, 64);
            pj0 += __shfl_xor(pj0, d, 64); pj1 += __shfl_xor(pj1, d, 64);
            pj2 += __shfl_xor(pj2, d, 64); pj3 += __shfl_xor(pj3, d, 64);
        }
        if (col == 0) {
            int nb = nodeBase + kg * 4;
            ai[(nb + 0) * HEADS + w] = pi0; aj[(nb + 0) * HEADS + w] = pj0;
            ai[(nb + 1) * HEADS + w] = pi1; aj[(nb + 1) * HEADS + w] = pj1;
            ai[(nb + 2) * HEADS + w] = pi2; aj[(nb + 2) * HEADS + w] = pj2;
            ai[(nb + 3) * HEADS + w] = pi3; aj[(nb + 3) * HEADS + w] = pj3;
        }
    }
}

// ---- Kernel 2: per-slice aggregation with LDS accumulators ---------------
// One block per 256-node slice. Edges are contiguous in seg[slice]. 16 lanes
// per edge read the 128B hb row coalesced; accumulate into LDS f32 (fast LDS
// atomics, no global atomics anywhere); normalize + dense out write.
__global__ __launch_bounds__(512) void agg_kernel(
    const int2* __restrict__ seg, const int* __restrict__ scursor,
    const ushort* __restrict__ hb, const float* __restrict__ ai,
    const float* __restrict__ aj, float* __restrict__ out)
{
    __shared__ float outa[SLICE_NODES][OUT_ALL];  // 64 KB
    __shared__ float den[SLICE_NODES][HEADS];     // 4 KB
    __shared__ float als[SLICE_NODES][HEADS];     // 4 KB

    int s = blockIdx.x;
    int nbase = s << SLICE_SHIFT;
    int nloc = N_NODES - nbase; if (nloc > SLICE_NODES) nloc = SLICE_NODES;

    for (int i = threadIdx.x; i < SLICE_NODES * OUT_ALL; i += 512)
        ((float*)outa)[i] = 0.f;
    for (int i = threadIdx.x; i < SLICE_NODES * HEADS; i += 512) {
        ((float*)den)[i] = 0.f;
        ((float*)als)[i] = (i < nloc * HEADS) ? ai[(size_t)nbase * HEADS + i] : 0.f;
    }
    __syncthreads();

    int total = scursor[s]; if (total > SEG_CAP) total = SEG_CAP;
    int g    = threadIdx.x >> 4;   // group 0..31, one edge per group-iter
    int sub  = threadIdx.x & 15;
    int head = sub >> 2;
    const int2* sp = seg + (size_t)s * SEG_CAP;

    for (int i = g; i < total; i += 32) {
        int2 e = sp[i];                           // broadcast within group
        int d = e.y & (SLICE_NODES - 1);
        float av = als[d][head] + aj[(size_t)e.x * HEADS + head];
        av = av > 0.f ? av : 0.01f * av;
        float ex = __expf(av);
        ushort4 hv = *(const ushort4*)(hb + (size_t)e.x * OUT_ALL + sub * 4);
        atomicAdd(&outa[d][sub * 4 + 0], ex * bf2f(hv.x));
        atomicAdd(&outa[d][sub * 4 + 1], ex * bf2f(hv.y));
        atomicAdd(&outa[d][sub * 4 + 2], ex * bf2f(hv.z));
        atomicAdd(&outa[d][sub * 4 + 3], ex * bf2f(hv.w));
        if ((sub & 3) == 0) atomicAdd(&den[d][head], ex);
    }
    __syncthreads();

    for (int idx = threadIdx.x; idx < nloc * 16; idx += 512) {
        int n = idx >> 4, q = idx & 15;
        float inv = 1.0f / (den[n][q >> 2] + 1e-16f);
        float4 v = *(float4*)&outa[n][q * 4];
        v.x *= inv; v.y *= inv; v.z *= inv; v.w *= inv;
        *(float4*)(out + (size_t)(nbase + n) * OUT_ALL + q * 4) = v;
    }
}

extern "C" void kernel_launch(void* const* d_in, const int* in_sizes, int n_in,
                              void* d_out, int out_size, void* d_ws, size_t ws_size,
                              hipStream_t stream) {
    const float* x     = (const float*)d_in[0];
    const int*   ei    = (const int*)d_in[1];
    const float* W     = (const float*)d_in[2];
    const float* att_i = (const float*)d_in[3];
    const float* att_j = (const float*)d_in[4];
    float* out = (float*)d_out;

    char* ws = (char*)d_ws;
    size_t off = 0;
    auto alloc = [&](size_t bytes) {
        void* p = ws + off;
        off += (bytes + 255) & ~(size_t)255;
        return p;
    };
    ushort* hb      = (ushort*)alloc((size_t)N_NODES * OUT_ALL * 2);   // 12.8 MB
    float*  ai      = (float*)alloc((size_t)N_NODES * HEADS * 4);      // 1.6 MB
    float*  aj      = (float*)alloc((size_t)N_NODES * HEADS * 4);      // 1.6 MB
    int*    scursor = (int*)alloc((size_t)NSLICES * 4);                // 1.6 KB
    int2*   seg     = (int2*)alloc((size_t)NSLICES * SEG_CAP * 8);     // 14.4 MB

    hipMemsetAsync(scursor, 0, (size_t)NSLICES * 4, stream);
    proj_bin_kernel<<<TOTAL_BLOCKS, 256, 0, stream>>>(
        x, W, att_i, att_j, ei, hb, ai, aj, scursor, seg);
    agg_kernel<<<NSLICES, 512, 0, stream>>>(seg, scursor, hb, ai, aj, out);
}

// Round 11
// 117.660 us; speedup vs baseline: 6.7677x; 6.7677x over previous
//
#include <hip/hip_runtime.h>

typedef __attribute__((ext_vector_type(8))) short short8;
typedef __attribute__((ext_vector_type(4))) float f32x4;

#define N_NODES 100000
#define N_EDGES 1600000
#define IN_F 128
#define OUT_ALL 64   // HEADS*OUT_F
#define HEADS 4
#define OUT_F 16
#define NTILES (N_NODES / 16)          // 6250
#define BIN_BLOCKS 512
#define EPB (N_EDGES / BIN_BLOCKS)     // 3125 edges per bin block
#define PROJ_BLOCKS 1536
#define TOTAL_BLOCKS (BIN_BLOCKS + PROJ_BLOCKS)
#define SLICE_SHIFT 8
#define SLICE_NODES 256
#define NSLICES ((N_NODES + SLICE_NODES - 1) / SLICE_NODES)   // 391
#define SEG_CAP 4608                   // avg 4096 + 8 sigma
#define HALF_NODES 128
#define SORT_CAP 2560                  // half-slice: avg 2048 + 11 sigma

static __device__ __forceinline__ ushort f2bf(float f) {
    unsigned u = __float_as_uint(f);
    return (ushort)((u + 0x7FFF + ((u >> 16) & 1)) >> 16);   // RN, no NaN inputs
}
static __device__ __forceinline__ float bf2f(ushort b) {
    return __uint_as_float(((unsigned)b) << 16);
}
static __device__ __forceinline__ short8 pack_bf16x8(float4 f0, float4 f1) {
    union { unsigned u[4]; short8 s; } r;
    asm("v_cvt_pk_bf16_f32 %0, %1, %2" : "=v"(r.u[0]) : "v"(f0.x), "v"(f0.y));
    asm("v_cvt_pk_bf16_f32 %0, %1, %2" : "=v"(r.u[1]) : "v"(f0.z), "v"(f0.w));
    asm("v_cvt_pk_bf16_f32 %0, %1, %2" : "=v"(r.u[2]) : "v"(f1.x), "v"(f1.y));
    asm("v_cvt_pk_bf16_f32 %0, %1, %2" : "=v"(r.u[3]) : "v"(f1.z), "v"(f1.w));
    return r.s;
}

// ---- Kernel 1: fused MFMA projection + slice-binning (unchanged R10) -----
__global__ __launch_bounds__(256) void proj_bin_kernel(
    const float* __restrict__ x, const float* __restrict__ W,
    const float* __restrict__ att_i, const float* __restrict__ att_j,
    const int* __restrict__ ei,
    ushort* __restrict__ hb, float* __restrict__ ai, float* __restrict__ aj,
    int* __restrict__ scursor, int2* __restrict__ seg)
{
    __shared__ int2 est[EPB];                 // 25.0 KB
    __shared__ int  cnt[NSLICES];             // 1.6 KB
    __shared__ int  gbase[NSLICES];           // 1.6 KB
    __shared__ int  run[NSLICES];             // 1.6 KB

    if (blockIdx.x < BIN_BLOCKS) {
        int base = blockIdx.x * EPB;
        for (int i = threadIdx.x; i < EPB; i += 256) {
            int2 e;
            e.x = ei[base + i];               // src
            e.y = ei[N_EDGES + base + i];     // dst
            est[i] = e;
        }
        for (int s = threadIdx.x; s < NSLICES; s += 256) { cnt[s] = 0; run[s] = 0; }
        __syncthreads();
        for (int i = threadIdx.x; i < EPB; i += 256)
            atomicAdd(&cnt[est[i].y >> SLICE_SHIFT], 1);
        __syncthreads();
        for (int s = threadIdx.x; s < NSLICES; s += 256) {
            int c = cnt[s];
            gbase[s] = c ? atomicAdd(&scursor[s], c) : 0;
        }
        __syncthreads();
        for (int i = threadIdx.x; i < EPB; i += 256) {
            int2 e = est[i];
            int s = e.y >> SLICE_SHIFT;
            int p = gbase[s] + atomicAdd(&run[s], 1);
            if (p < SEG_CAP) seg[(size_t)s * SEG_CAP + p] = e;
        }
        return;
    }

    int bproj = blockIdx.x - BIN_BLOCKS;       // 0..1535
    const int nproj = PROJ_BLOCKS;

    int w   = threadIdx.x >> 6;    // wave id == head == 16-col n-tile
    int l   = threadIdx.x & 63;
    int col = l & 15;
    int kg  = l >> 4;              // k-group 0..3 (8 k each)

    short8 bw[4];
    #pragma unroll
    for (int m = 0; m < 4; ++m) {
        const float* wp = W + (size_t)(w * 16 + col) * IN_F + m * 32 + kg * 8;
        float4 f0 = *(const float4*)wp;
        float4 f1 = *(const float4*)(wp + 4);
        bw[m] = pack_bf16x8(f0, f1);
    }
    float atv_i = att_i[w * OUT_F + col];
    float atv_j = att_j[w * OUT_F + col];

    for (int t = bproj; t < NTILES; t += nproj) {
        int nodeBase = t * 16;
        const float* xp = x + (size_t)(nodeBase + col) * IN_F + kg * 8;
        short8 a[4];
        #pragma unroll
        for (int m = 0; m < 4; ++m) {
            float4 f0 = *(const float4*)(xp + m * 32);
            float4 f1 = *(const float4*)(xp + m * 32 + 4);
            a[m] = pack_bf16x8(f0, f1);
        }
        f32x4 acc = {0.f, 0.f, 0.f, 0.f};
        #pragma unroll
        for (int m = 0; m < 4; ++m)
            acc = __builtin_amdgcn_mfma_f32_16x16x32_bf16(a[m], bw[m], acc, 0, 0, 0);

        #pragma unroll
        for (int r = 0; r < 4; ++r)
            hb[(size_t)(nodeBase + kg * 4 + r) * OUT_ALL + w * 16 + col] = f2bf(acc[r]);

        float pi0 = acc[0] * atv_i, pi1 = acc[1] * atv_i,
              pi2 = acc[2] * atv_i, pi3 = acc[3] * atv_i;
        float pj0 = acc[0] * atv_j, pj1 = acc[1] * atv_j,
              pj2 = acc[2] * atv_j, pj3 = acc[3] * atv_j;
        #pragma unroll
        for (int d = 1; d < 16; d <<= 1) {
            pi0 += __shfl_xor(pi0, d, 64); pi1 += __shfl_xor(pi1, d, 64);
            pi2 += __shfl_xor(pi2, d, 64); pi3 += __shfl_xor(pi3, d, 64);
            pj0 += __shfl_xor(pj0, d, 64); pj1 += __shfl_xor(pj1, d, 64);
            pj2 += __shfl_xor(pj2, d, 64); pj3 += __shfl_xor(pj3, d, 64);
        }
        if (col == 0) {
            int nb = nodeBase + kg * 4;
            ai[(nb + 0) * HEADS + w] = pi0; aj[(nb + 0) * HEADS + w] = pj0;
            ai[(nb + 1) * HEADS + w] = pi1; aj[(nb + 1) * HEADS + w] = pj1;
            ai[(nb + 2) * HEADS + w] = pi2; aj[(nb + 2) * HEADS + w] = pj2;
            ai[(nb + 3) * HEADS + w] = pi3; aj[(nb + 3) * HEADS + w] = pj3;
        }
    }
}

// ---- Kernel 2: half-slice counting-sort + register gather ----------------
// Block = 128 nodes (782 blocks). Counting-sort the slice segment's edges
// for this half into LDS (atomics only on 128 bin counters), then R8-style
// register gather: 16 lanes/node, acc in VGPRs, 128B coalesced hb row/edge.
// No accumulation atomics anywhere.
__global__ __launch_bounds__(512) void agg_kernel(
    const int2* __restrict__ seg, const int* __restrict__ scursor,
    const ushort* __restrict__ hb, const float* __restrict__ ai,
    const float* __restrict__ aj, float* __restrict__ out)
{
    __shared__ int sorted_src[SORT_CAP];      // 10.2 KB
    __shared__ int cnt[HALF_NODES];
    __shared__ int run[HALF_NODES];
    __shared__ int rowptr[HALF_NODES + 1];

    int s     = blockIdx.x >> 1;
    int half  = blockIdx.x & 1;
    int nbase = (s << SLICE_SHIFT) + half * HALF_NODES;
    int total = scursor[s]; if (total > SEG_CAP) total = SEG_CAP;
    const int2* sp = seg + (size_t)s * SEG_CAP;

    for (int i = threadIdx.x; i < HALF_NODES; i += 512) { cnt[i] = 0; run[i] = 0; }
    __syncthreads();

    // pass 1: histogram of this half's dst (seg is contiguous -> L2 stream)
    for (int i = threadIdx.x; i < total; i += 512) {
        int d = sp[i].y & (SLICE_NODES - 1);
        if ((d >> 7) == half) atomicAdd(&cnt[d & (HALF_NODES - 1)], 1);
    }
    __syncthreads();

    // exclusive scan of 128 bins by wave 0 (two 64-lane shfl chunks)
    if (threadIdx.x < 64) {
        int l = threadIdx.x;
        int base = 0;
        #pragma unroll
        for (int c = 0; c < 2; ++c) {
            int v = cnt[c * 64 + l];
            int inc = v;
            #pragma unroll
            for (int d = 1; d < 64; d <<= 1) {
                int t = __shfl_up(inc, d, 64);
                if (l >= d) inc += t;
            }
            rowptr[c * 64 + l] = base + inc - v;
            base += __shfl(inc, 63, 64);
        }
        if (l == 0) rowptr[HALF_NODES] = base;
    }
    __syncthreads();

    // pass 2: scatter src into sorted order (LDS)
    for (int i = threadIdx.x; i < total; i += 512) {
        int2 e = sp[i];
        int d = e.y & (SLICE_NODES - 1);
        if ((d >> 7) == half) {
            int lb = d & (HALF_NODES - 1);
            int p = rowptr[lb] + atomicAdd(&run[lb], 1);
            if (p < SORT_CAP) sorted_src[p] = e.x;
        }
    }
    __syncthreads();

    // register gather: 32 groups of 16 lanes, 4 node-iterations
    int g    = threadIdx.x >> 4;
    int sub  = threadIdx.x & 15;
    int head = sub >> 2;
    for (int n = g; n < HALF_NODES; n += 32) {
        int node = nbase + n;
        if (node >= N_NODES) continue;
        int beg = rowptr[n], end = rowptr[n + 1];
        if (end > SORT_CAP) end = SORT_CAP;
        float aiv = ai[(size_t)node * HEADS + head];
        float4 acc = {0.f, 0.f, 0.f, 0.f};
        float  den = 0.f;
        for (int k = beg; k < end; ++k) {
            int src = sorted_src[k];             // LDS broadcast
            float av = aiv + aj[(size_t)src * HEADS + head];
            av = av > 0.f ? av : 0.01f * av;
            float ex = __expf(av);
            den += ex;
            ushort4 hv = *(const ushort4*)(hb + (size_t)src * OUT_ALL + sub * 4);
            acc.x += ex * bf2f(hv.x); acc.y += ex * bf2f(hv.y);
            acc.z += ex * bf2f(hv.z); acc.w += ex * bf2f(hv.w);
        }
        float inv = 1.0f / (den + 1e-16f);
        acc.x *= inv; acc.y *= inv; acc.z *= inv; acc.w *= inv;
        *(float4*)(out + (size_t)node * OUT_ALL + sub * 4) = acc;
    }
}

extern "C" void kernel_launch(void* const* d_in, const int* in_sizes, int n_in,
                              void* d_out, int out_size, void* d_ws, size_t ws_size,
                              hipStream_t stream) {
    const float* x     = (const float*)d_in[0];
    const int*   ei    = (const int*)d_in[1];
    const float* W     = (const float*)d_in[2];
    const float* att_i = (const float*)d_in[3];
    const float* att_j = (const float*)d_in[4];
    float* out = (float*)d_out;

    char* ws = (char*)d_ws;
    size_t off = 0;
    auto alloc = [&](size_t bytes) {
        void* p = ws + off;
        off += (bytes + 255) & ~(size_t)255;
        return p;
    };
    ushort* hb      = (ushort*)alloc((size_t)N_NODES * OUT_ALL * 2);   // 12.8 MB
    float*  ai      = (float*)alloc((size_t)N_NODES * HEADS * 4);      // 1.6 MB
    float*  aj      = (float*)alloc((size_t)N_NODES * HEADS * 4);      // 1.6 MB
    int*    scursor = (int*)alloc((size_t)NSLICES * 4);                // 1.6 KB
    int2*   seg     = (int2*)alloc((size_t)NSLICES * SEG_CAP * 8);     // 14.4 MB

    hipMemsetAsync(scursor, 0, (size_t)NSLICES * 4, stream);
    proj_bin_kernel<<<TOTAL_BLOCKS, 256, 0, stream>>>(
        x, W, att_i, att_j, ei, hb, ai, aj, scursor, seg);
    agg_kernel<<<NSLICES * 2, 512, 0, stream>>>(seg, scursor, hb, ai, aj, out);
}

// Round 12
// 111.822 us; speedup vs baseline: 7.1211x; 1.0522x over previous
//
#include <hip/hip_runtime.h>

typedef __attribute__((ext_vector_type(8))) short short8;
typedef __attribute__((ext_vector_type(4))) float f32x4;

#define N_NODES 100000
#define N_EDGES 1600000
#define IN_F 128
#define OUT_ALL 64   // HEADS*OUT_F
#define HEADS 4
#define OUT_F 16
#define NTILES (N_NODES / 16)          // 6250
#define BIN_BLOCKS 128
#define EPB (N_EDGES / BIN_BLOCKS)     // 12500 edges per bin block
#define PROJ_BLOCKS 1920
#define TOTAL_BLOCKS (BIN_BLOCKS + PROJ_BLOCKS)   // 2048
#define SLICE_SHIFT 8
#define SLICE_NODES 256
#define NSLICES ((N_NODES + SLICE_NODES - 1) / SLICE_NODES)   // 391
#define SEG_CAP 4608                   // avg 4096 + 8 sigma
#define HALF_NODES 128
#define SORT_CAP 2560                  // half-slice: avg 2048 + 11 sigma

static __device__ __forceinline__ ushort f2bf(float f) {
    unsigned u = __float_as_uint(f);
    return (ushort)((u + 0x7FFF + ((u >> 16) & 1)) >> 16);   // RN, no NaN inputs
}
static __device__ __forceinline__ float bf2f(ushort b) {
    return __uint_as_float(((unsigned)b) << 16);
}
static __device__ __forceinline__ short8 pack_bf16x8(float4 f0, float4 f1) {
    union { unsigned u[4]; short8 s; } r;
    asm("v_cvt_pk_bf16_f32 %0, %1, %2" : "=v"(r.u[0]) : "v"(f0.x), "v"(f0.y));
    asm("v_cvt_pk_bf16_f32 %0, %1, %2" : "=v"(r.u[1]) : "v"(f0.z), "v"(f0.w));
    asm("v_cvt_pk_bf16_f32 %0, %1, %2" : "=v"(r.u[2]) : "v"(f1.x), "v"(f1.y));
    asm("v_cvt_pk_bf16_f32 %0, %1, %2" : "=v"(r.u[3]) : "v"(f1.z), "v"(f1.w));
    return r.s;
}

// ---- Kernel 0: fold att into W: wiwj[k][c] = sum_f W[h*16+f,k]*att(c)[h,f]
// c 0..3 -> att_i heads 0..3 ; c 4..7 -> att_j heads 0..3.  (128x8 f32)
__global__ __launch_bounds__(256) void prep_kernel(
    const float* __restrict__ W, const float* __restrict__ att_i,
    const float* __restrict__ att_j, float* __restrict__ wiwj)
{
    int idx = blockIdx.x * 256 + threadIdx.x;
    if (idx >= IN_F * 8) return;
    int k = idx >> 3, c = idx & 7;
    int h = c & 3;
    const float* att = (c < 4) ? att_i : att_j;
    float s = 0.f;
    #pragma unroll
    for (int f = 0; f < 16; ++f)
        s += W[(size_t)(h * 16 + f) * IN_F + k] * att[h * OUT_F + f];
    wiwj[k * 8 + c] = s;
}

// ---- Kernel 1: fused MFMA projection (+MFMA att dots) + slice binning ----
// Bin role (blocks 0..127): two int4 passes over this block's 12500 edges
// (ei is L2/L3-resident, no LDS staging): histogram per 256-node slice ->
// ONE global atomicAdd per (block,slice) (50K total), then scatter edges as
// dense ~256B runs into the slice's contiguous segment.
// Proj role (blocks 128..2047): R6 MFMA projection; ai/aj now come from a
// 2nd MFMA against the folded wiwj (cols 0..7) instead of shuffle reduction.
__global__ __launch_bounds__(256) void proj_bin_kernel(
    const float* __restrict__ x, const float* __restrict__ W,
    const float* __restrict__ wiwj, const int* __restrict__ ei,
    ushort* __restrict__ hb, float* __restrict__ ai, float* __restrict__ aj,
    int* __restrict__ scursor, int2* __restrict__ seg)
{
    __shared__ int cnt[NSLICES];              // 1.6 KB
    __shared__ int gbase[NSLICES];            // 1.6 KB
    __shared__ int run[NSLICES];              // 1.6 KB

    if (blockIdx.x < BIN_BLOCKS) {
        int base = blockIdx.x * EPB;
        const int4* __restrict__ srcp = (const int4*)(ei + base);
        const int4* __restrict__ dstp = (const int4*)(ei + N_EDGES + base);
        for (int s = threadIdx.x; s < NSLICES; s += 256) { cnt[s] = 0; run[s] = 0; }
        __syncthreads();
        for (int i = threadIdx.x; i < EPB / 4; i += 256) {
            int4 d = dstp[i];
            atomicAdd(&cnt[d.x >> SLICE_SHIFT], 1);
            atomicAdd(&cnt[d.y >> SLICE_SHIFT], 1);
            atomicAdd(&cnt[d.z >> SLICE_SHIFT], 1);
            atomicAdd(&cnt[d.w >> SLICE_SHIFT], 1);
        }
        __syncthreads();
        for (int s = threadIdx.x; s < NSLICES; s += 256) {
            int c = cnt[s];
            gbase[s] = c ? atomicAdd(&scursor[s], c) : 0;
        }
        __syncthreads();
        for (int i = threadIdx.x; i < EPB / 4; i += 256) {
            int4 sv = srcp[i];
            int4 dv = dstp[i];
            int ss, p;
            ss = dv.x >> SLICE_SHIFT; p = gbase[ss] + atomicAdd(&run[ss], 1);
            if (p < SEG_CAP) seg[(size_t)ss * SEG_CAP + p] = make_int2(sv.x, dv.x);
            ss = dv.y >> SLICE_SHIFT; p = gbase[ss] + atomicAdd(&run[ss], 1);
            if (p < SEG_CAP) seg[(size_t)ss * SEG_CAP + p] = make_int2(sv.y, dv.y);
            ss = dv.z >> SLICE_SHIFT; p = gbase[ss] + atomicAdd(&run[ss], 1);
            if (p < SEG_CAP) seg[(size_t)ss * SEG_CAP + p] = make_int2(sv.z, dv.z);
            ss = dv.w >> SLICE_SHIFT; p = gbase[ss] + atomicAdd(&run[ss], 1);
            if (p < SEG_CAP) seg[(size_t)ss * SEG_CAP + p] = make_int2(sv.w, dv.w);
        }
        return;
    }

    int bproj = blockIdx.x - BIN_BLOCKS;       // 0..1919
    const int nproj = PROJ_BLOCKS;

    int w   = threadIdx.x >> 6;    // wave id == head == 16-col n-tile
    int l   = threadIdx.x & 63;
    int col = l & 15;
    int kg  = l >> 4;              // k-group 0..3 (8 k each)

    // B-frags: rows of W (f32 -> bf16), one per 32-wide K block
    short8 bw[4];
    #pragma unroll
    for (int m = 0; m < 4; ++m) {
        const float* wp = W + (size_t)(w * 16 + col) * IN_F + m * 32 + kg * 8;
        float4 f0 = *(const float4*)wp;
        float4 f1 = *(const float4*)(wp + 4);
        bw[m] = pack_bf16x8(f0, f1);
    }
    // B-frags for the att-dot MFMA: cols 0..7 = wiwj, cols 8..15 = 0
    short8 bwd[4];
    #pragma unroll
    for (int m = 0; m < 4; ++m) {
        float v[8];
        #pragma unroll
        for (int j = 0; j < 8; ++j)
            v[j] = (col < 8) ? wiwj[(size_t)(m * 32 + kg * 8 + j) * 8 + col] : 0.f;
        bwd[m] = pack_bf16x8(float4{v[0], v[1], v[2], v[3]},
                             float4{v[4], v[5], v[6], v[7]});
    }

    for (int t = bproj; t < NTILES; t += nproj) {
        int nodeBase = t * 16;
        const float* xp = x + (size_t)(nodeBase + col) * IN_F + kg * 8;
        short8 a[4];
        #pragma unroll
        for (int m = 0; m < 4; ++m) {
            float4 f0 = *(const float4*)(xp + m * 32);
            float4 f1 = *(const float4*)(xp + m * 32 + 4);
            a[m] = pack_bf16x8(f0, f1);
        }
        f32x4 acc = {0.f, 0.f, 0.f, 0.f};
        f32x4 accd = {0.f, 0.f, 0.f, 0.f};
        #pragma unroll
        for (int m = 0; m < 4; ++m) {
            acc  = __builtin_amdgcn_mfma_f32_16x16x32_bf16(a[m], bw[m],  acc,  0, 0, 0);
            accd = __builtin_amdgcn_mfma_f32_16x16x32_bf16(a[m], bwd[m], accd, 0, 0, 0);
        }

        // h (bf16) store: lane covers col, rows kg*4+r
        #pragma unroll
        for (int r = 0; r < 4; ++r)
            hb[(size_t)(nodeBase + kg * 4 + r) * OUT_ALL + w * 16 + col] = f2bf(acc[r]);

        // att dots straight from the accumulator: col 0..3 -> ai, 4..7 -> aj
        if (col < 4) {
            #pragma unroll
            for (int r = 0; r < 4; ++r)
                ai[(size_t)(nodeBase + kg * 4 + r) * HEADS + col] = accd[r];
        } else if (col < 8) {
            #pragma unroll
            for (int r = 0; r < 4; ++r)
                aj[(size_t)(nodeBase + kg * 4 + r) * HEADS + (col - 4)] = accd[r];
        }
    }
}

// ---- Kernel 2: half-slice counting-sort + register gather (unchanged) ----
__global__ __launch_bounds__(512) void agg_kernel(
    const int2* __restrict__ seg, const int* __restrict__ scursor,
    const ushort* __restrict__ hb, const float* __restrict__ ai,
    const float* __restrict__ aj, float* __restrict__ out)
{
    __shared__ int sorted_src[SORT_CAP];      // 10.2 KB
    __shared__ int cnt[HALF_NODES];
    __shared__ int run[HALF_NODES];
    __shared__ int rowptr[HALF_NODES + 1];

    int s     = blockIdx.x >> 1;
    int half  = blockIdx.x & 1;
    int nbase = (s << SLICE_SHIFT) + half * HALF_NODES;
    int total = scursor[s]; if (total > SEG_CAP) total = SEG_CAP;
    const int2* sp = seg + (size_t)s * SEG_CAP;

    for (int i = threadIdx.x; i < HALF_NODES; i += 512) { cnt[i] = 0; run[i] = 0; }
    __syncthreads();

    for (int i = threadIdx.x; i < total; i += 512) {
        int d = sp[i].y & (SLICE_NODES - 1);
        if ((d >> 7) == half) atomicAdd(&cnt[d & (HALF_NODES - 1)], 1);
    }
    __syncthreads();

    if (threadIdx.x < 64) {
        int l = threadIdx.x;
        int base = 0;
        #pragma unroll
        for (int c = 0; c < 2; ++c) {
            int v = cnt[c * 64 + l];
            int inc = v;
            #pragma unroll
            for (int d = 1; d < 64; d <<= 1) {
                int t = __shfl_up(inc, d, 64);
                if (l >= d) inc += t;
            }
            rowptr[c * 64 + l] = base + inc - v;
            base += __shfl(inc, 63, 64);
        }
        if (l == 0) rowptr[HALF_NODES] = base;
    }
    __syncthreads();

    for (int i = threadIdx.x; i < total; i += 512) {
        int2 e = sp[i];
        int d = e.y & (SLICE_NODES - 1);
        if ((d >> 7) == half) {
            int lb = d & (HALF_NODES - 1);
            int p = rowptr[lb] + atomicAdd(&run[lb], 1);
            if (p < SORT_CAP) sorted_src[p] = e.x;
        }
    }
    __syncthreads();

    int g    = threadIdx.x >> 4;
    int sub  = threadIdx.x & 15;
    int head = sub >> 2;
    for (int n = g; n < HALF_NODES; n += 32) {
        int node = nbase + n;
        if (node >= N_NODES) continue;
        int beg = rowptr[n], end = rowptr[n + 1];
        if (end > SORT_CAP) end = SORT_CAP;
        float aiv = ai[(size_t)node * HEADS + head];
        float4 acc = {0.f, 0.f, 0.f, 0.f};
        float  den = 0.f;
        for (int k = beg; k < end; ++k) {
            int src = sorted_src[k];             // LDS broadcast
            float av = aiv + aj[(size_t)src * HEADS + head];
            av = av > 0.f ? av : 0.01f * av;
            float ex = __expf(av);
            den += ex;
            ushort4 hv = *(const ushort4*)(hb + (size_t)src * OUT_ALL + sub * 4);
            acc.x += ex * bf2f(hv.x); acc.y += ex * bf2f(hv.y);
            acc.z += ex * bf2f(hv.z); acc.w += ex * bf2f(hv.w);
        }
        float inv = 1.0f / (den + 1e-16f);
        acc.x *= inv; acc.y *= inv; acc.z *= inv; acc.w *= inv;
        *(float4*)(out + (size_t)node * OUT_ALL + sub * 4) = acc;
    }
}

extern "C" void kernel_launch(void* const* d_in, const int* in_sizes, int n_in,
                              void* d_out, int out_size, void* d_ws, size_t ws_size,
                              hipStream_t stream) {
    const float* x     = (const float*)d_in[0];
    const int*   ei    = (const int*)d_in[1];
    const float* W     = (const float*)d_in[2];
    const float* att_i = (const float*)d_in[3];
    const float* att_j = (const float*)d_in[4];
    float* out = (float*)d_out;

    char* ws = (char*)d_ws;
    size_t off = 0;
    auto alloc = [&](size_t bytes) {
        void* p = ws + off;
        off += (bytes + 255) & ~(size_t)255;
        return p;
    };
    ushort* hb      = (ushort*)alloc((size_t)N_NODES * OUT_ALL * 2);   // 12.8 MB
    float*  ai      = (float*)alloc((size_t)N_NODES * HEADS * 4);      // 1.6 MB
    float*  aj      = (float*)alloc((size_t)N_NODES * HEADS * 4);      // 1.6 MB
    float*  wiwj    = (float*)alloc((size_t)IN_F * 8 * 4);             // 4 KB
    int*    scursor = (int*)alloc((size_t)NSLICES * 4);                // 1.6 KB
    int2*   seg     = (int2*)alloc((size_t)NSLICES * SEG_CAP * 8);     // 14.4 MB

    hipMemsetAsync(scursor, 0, (size_t)NSLICES * 4, stream);
    prep_kernel<<<(IN_F * 8 + 255) / 256, 256, 0, stream>>>(W, att_i, att_j, wiwj);
    proj_bin_kernel<<<TOTAL_BLOCKS, 256, 0, stream>>>(
        x, W, wiwj, ei, hb, ai, aj, scursor, seg);
    agg_kernel<<<NSLICES * 2, 512, 0, stream>>>(seg, scursor, hb, ai, aj, out);
}

// Round 13
// 108.939 us; speedup vs baseline: 7.3095x; 1.0265x over previous
//
#include <hip/hip_runtime.h>

typedef __attribute__((ext_vector_type(8))) short short8;
typedef __attribute__((ext_vector_type(4))) float f32x4;

#define N_NODES 100000
#define N_EDGES 1600000
#define IN_F 128
#define OUT_ALL 64   // HEADS*OUT_F
#define HEADS 4
#define OUT_F 16
#define NTILES (N_NODES / 16)          // 6250
#define BIN_BLOCKS 250
#define EPB (N_EDGES / BIN_BLOCKS)     // 6400 edges per bin block
#define TOTAL_BLOCKS 2048
#define PROJ_BLOCKS (TOTAL_BLOCKS - BIN_BLOCKS)   // 1798
#define SLICE_SHIFT 8
#define SLICE_NODES 256
#define NSLICES ((N_NODES + SLICE_NODES - 1) / SLICE_NODES)   // 391
#define SEG_CAP 4608                   // avg 4096 + 8 sigma
#define QUARTER_NODES 64
#define SORT_CAP 1280                  // quarter: avg 1024 + 8 sigma

static __device__ __forceinline__ ushort f2bf(float f) {
    unsigned u = __float_as_uint(f);
    return (ushort)((u + 0x7FFF + ((u >> 16) & 1)) >> 16);   // RN, no NaN inputs
}
static __device__ __forceinline__ float bf2f(ushort b) {
    return __uint_as_float(((unsigned)b) << 16);
}
static __device__ __forceinline__ short8 pack_bf16x8(float4 f0, float4 f1) {
    union { unsigned u[4]; short8 s; } r;
    asm("v_cvt_pk_bf16_f32 %0, %1, %2" : "=v"(r.u[0]) : "v"(f0.x), "v"(f0.y));
    asm("v_cvt_pk_bf16_f32 %0, %1, %2" : "=v"(r.u[1]) : "v"(f0.z), "v"(f0.w));
    asm("v_cvt_pk_bf16_f32 %0, %1, %2" : "=v"(r.u[2]) : "v"(f1.x), "v"(f1.y));
    asm("v_cvt_pk_bf16_f32 %0, %1, %2" : "=v"(r.u[3]) : "v"(f1.z), "v"(f1.w));
    return r.s;
}

// ---- Kernel 0: fold att into W + zero scursor ----------------------------
// wiwj[k][c] = sum_f W[h*16+f,k]*att(c)[h,f]; c<4 -> att_i, c>=4 -> att_j.
__global__ __launch_bounds__(256) void prep_kernel(
    const float* __restrict__ W, const float* __restrict__ att_i,
    const float* __restrict__ att_j, float* __restrict__ wiwj,
    int* __restrict__ scursor)
{
    int idx = blockIdx.x * 256 + threadIdx.x;
    if (idx < NSLICES) scursor[idx] = 0;
    if (idx >= IN_F * 8) return;
    int k = idx >> 3, c = idx & 7;
    int h = c & 3;
    const float* att = (c < 4) ? att_i : att_j;
    float s = 0.f;
    #pragma unroll
    for (int f = 0; f < 16; ++f)
        s += W[(size_t)(h * 16 + f) * IN_F + k] * att[h * OUT_F + f];
    wiwj[k * 8 + c] = s;
}

// ---- Kernel 1: fused MFMA projection (+MFMA att dots) + slice binning ----
// Bin role (blocks 0..249): two int4 passes over this block's 6400 edges:
// LDS histogram per 256-node slice -> ONE global atomicAdd per (block,slice)
// (~98K total), then scatter edges as dense ~128B runs into the slice's
// contiguous segment.
// Proj role (blocks 250..2047): MFMA projection; ai/aj from a 2nd MFMA
// against folded wiwj (cols 0..7).
__global__ __launch_bounds__(256) void proj_bin_kernel(
    const float* __restrict__ x, const float* __restrict__ W,
    const float* __restrict__ wiwj, const int* __restrict__ ei,
    ushort* __restrict__ hb, float* __restrict__ ai, float* __restrict__ aj,
    int* __restrict__ scursor, int2* __restrict__ seg)
{
    __shared__ int cnt[NSLICES];              // 1.6 KB
    __shared__ int gbase[NSLICES];            // 1.6 KB
    __shared__ int run[NSLICES];              // 1.6 KB

    if (blockIdx.x < BIN_BLOCKS) {
        int base = blockIdx.x * EPB;
        const int4* __restrict__ srcp = (const int4*)(ei + base);
        const int4* __restrict__ dstp = (const int4*)(ei + N_EDGES + base);
        for (int s = threadIdx.x; s < NSLICES; s += 256) { cnt[s] = 0; run[s] = 0; }
        __syncthreads();
        for (int i = threadIdx.x; i < EPB / 4; i += 256) {
            int4 d = dstp[i];
            atomicAdd(&cnt[d.x >> SLICE_SHIFT], 1);
            atomicAdd(&cnt[d.y >> SLICE_SHIFT], 1);
            atomicAdd(&cnt[d.z >> SLICE_SHIFT], 1);
            atomicAdd(&cnt[d.w >> SLICE_SHIFT], 1);
        }
        __syncthreads();
        for (int s = threadIdx.x; s < NSLICES; s += 256) {
            int c = cnt[s];
            gbase[s] = c ? atomicAdd(&scursor[s], c) : 0;
        }
        __syncthreads();
        for (int i = threadIdx.x; i < EPB / 4; i += 256) {
            int4 sv = srcp[i];
            int4 dv = dstp[i];
            int ss, p;
            ss = dv.x >> SLICE_SHIFT; p = gbase[ss] + atomicAdd(&run[ss], 1);
            if (p < SEG_CAP) seg[(size_t)ss * SEG_CAP + p] = make_int2(sv.x, dv.x);
            ss = dv.y >> SLICE_SHIFT; p = gbase[ss] + atomicAdd(&run[ss], 1);
            if (p < SEG_CAP) seg[(size_t)ss * SEG_CAP + p] = make_int2(sv.y, dv.y);
            ss = dv.z >> SLICE_SHIFT; p = gbase[ss] + atomicAdd(&run[ss], 1);
            if (p < SEG_CAP) seg[(size_t)ss * SEG_CAP + p] = make_int2(sv.z, dv.z);
            ss = dv.w >> SLICE_SHIFT; p = gbase[ss] + atomicAdd(&run[ss], 1);
            if (p < SEG_CAP) seg[(size_t)ss * SEG_CAP + p] = make_int2(sv.w, dv.w);
        }
        return;
    }

    int bproj = blockIdx.x - BIN_BLOCKS;       // 0..1797
    const int nproj = PROJ_BLOCKS;

    int w   = threadIdx.x >> 6;    // wave id == head == 16-col n-tile
    int l   = threadIdx.x & 63;
    int col = l & 15;
    int kg  = l >> 4;              // k-group 0..3 (8 k each)

    // B-frags: rows of W (f32 -> bf16), one per 32-wide K block
    short8 bw[4];
    #pragma unroll
    for (int m = 0; m < 4; ++m) {
        const float* wp = W + (size_t)(w * 16 + col) * IN_F + m * 32 + kg * 8;
        float4 f0 = *(const float4*)wp;
        float4 f1 = *(const float4*)(wp + 4);
        bw[m] = pack_bf16x8(f0, f1);
    }
    // B-frags for the att-dot MFMA: cols 0..7 = wiwj, cols 8..15 = 0
    short8 bwd[4];
    #pragma unroll
    for (int m = 0; m < 4; ++m) {
        float v[8];
        #pragma unroll
        for (int j = 0; j < 8; ++j)
            v[j] = (col < 8) ? wiwj[(size_t)(m * 32 + kg * 8 + j) * 8 + col] : 0.f;
        bwd[m] = pack_bf16x8(float4{v[0], v[1], v[2], v[3]},
                             float4{v[4], v[5], v[6], v[7]});
    }

    for (int t = bproj; t < NTILES; t += nproj) {
        int nodeBase = t * 16;
        const float* xp = x + (size_t)(nodeBase + col) * IN_F + kg * 8;
        short8 a[4];
        #pragma unroll
        for (int m = 0; m < 4; ++m) {
            float4 f0 = *(const float4*)(xp + m * 32);
            float4 f1 = *(const float4*)(xp + m * 32 + 4);
            a[m] = pack_bf16x8(f0, f1);
        }
        f32x4 acc = {0.f, 0.f, 0.f, 0.f};
        f32x4 accd = {0.f, 0.f, 0.f, 0.f};
        #pragma unroll
        for (int m = 0; m < 4; ++m) {
            acc  = __builtin_amdgcn_mfma_f32_16x16x32_bf16(a[m], bw[m],  acc,  0, 0, 0);
            accd = __builtin_amdgcn_mfma_f32_16x16x32_bf16(a[m], bwd[m], accd, 0, 0, 0);
        }

        #pragma unroll
        for (int r = 0; r < 4; ++r)
            hb[(size_t)(nodeBase + kg * 4 + r) * OUT_ALL + w * 16 + col] = f2bf(acc[r]);

        if (col < 4) {
            #pragma unroll
            for (int r = 0; r < 4; ++r)
                ai[(size_t)(nodeBase + kg * 4 + r) * HEADS + col] = accd[r];
        } else if (col < 8) {
            #pragma unroll
            for (int r = 0; r < 4; ++r)
                aj[(size_t)(nodeBase + kg * 4 + r) * HEADS + (col - 4)] = accd[r];
        }
    }
}

// ---- Kernel 2: quarter-slice counting-sort + register gather -------------
// Block = 64 nodes (1564 blocks). Sort this quarter's edges into LDS, then
// one 8-lane group per node: per edge 1 LDS broadcast + 1 aj dword +
// 1 hb dwordx4 (16B); acc in VGPRs; no accumulation atomics.
__global__ __launch_bounds__(512) void agg_kernel(
    const int2* __restrict__ seg, const int* __restrict__ scursor,
    const ushort* __restrict__ hb, const float* __restrict__ ai,
    const float* __restrict__ aj, float* __restrict__ out)
{
    __shared__ int sorted_src[SORT_CAP];      // 5.1 KB
    __shared__ int cnt[QUARTER_NODES];
    __shared__ int run[QUARTER_NODES];
    __shared__ int rowptr[QUARTER_NODES + 1];

    int s       = blockIdx.x >> 2;
    int quarter = blockIdx.x & 3;
    int nbase   = (s << SLICE_SHIFT) + quarter * QUARTER_NODES;
    int total = scursor[s]; if (total > SEG_CAP) total = SEG_CAP;
    const int2* sp = seg + (size_t)s * SEG_CAP;

    for (int i = threadIdx.x; i < QUARTER_NODES; i += 512) { cnt[i] = 0; run[i] = 0; }
    __syncthreads();

    // pass 1: histogram of this quarter's dst (seg contiguous -> L2/L3 stream)
    for (int i = threadIdx.x; i < total; i += 512) {
        int d = sp[i].y & (SLICE_NODES - 1);
        if ((d >> 6) == quarter) atomicAdd(&cnt[d & (QUARTER_NODES - 1)], 1);
    }
    __syncthreads();

    // exclusive scan of 64 bins by wave 0
    if (threadIdx.x < 64) {
        int l = threadIdx.x;
        int v = cnt[l];
        int inc = v;
        #pragma unroll
        for (int d = 1; d < 64; d <<= 1) {
            int t = __shfl_up(inc, d, 64);
            if (l >= d) inc += t;
        }
        rowptr[l] = inc - v;
        if (l == 63) rowptr[64] = inc;
    }
    __syncthreads();

    // pass 2: scatter src into sorted order (LDS)
    for (int i = threadIdx.x; i < total; i += 512) {
        int2 e = sp[i];
        int d = e.y & (SLICE_NODES - 1);
        if ((d >> 6) == quarter) {
            int lb = d & (QUARTER_NODES - 1);
            int p = rowptr[lb] + atomicAdd(&run[lb], 1);
            if (p < SORT_CAP) sorted_src[p] = e.x;
        }
    }
    __syncthreads();

    // register gather: 64 groups of 8 lanes, one node each
    int g    = threadIdx.x >> 3;   // 0..63 == local node
    int sub  = threadIdx.x & 7;    // 8 lanes, 8 cols each
    int head = sub >> 1;
    int node = nbase + g;
    if (node >= N_NODES) return;
    int beg = rowptr[g], end = rowptr[g + 1];
    if (end > SORT_CAP) end = SORT_CAP;
    float aiv = ai[(size_t)node * HEADS + head];
    float acc[8] = {0.f, 0.f, 0.f, 0.f, 0.f, 0.f, 0.f, 0.f};
    float den = 0.f;
    for (int k = beg; k < end; ++k) {
        int src = sorted_src[k];               // LDS broadcast to 8 lanes
        float av = aiv + aj[(size_t)src * HEADS + head];
        av = av > 0.f ? av : 0.01f * av;
        float ex = __expf(av);
        den += ex;
        short8 hv = *(const short8*)(hb + (size_t)src * OUT_ALL + sub * 8);
        #pragma unroll
        for (int q = 0; q < 8; ++q)
            acc[q] += ex * bf2f((ushort)hv[q]);
    }
    float inv = 1.0f / (den + 1e-16f);
    float4 o0 = {acc[0] * inv, acc[1] * inv, acc[2] * inv, acc[3] * inv};
    float4 o1 = {acc[4] * inv, acc[5] * inv, acc[6] * inv, acc[7] * inv};
    float* op = out + (size_t)node * OUT_ALL + sub * 8;
    *(float4*)op = o0;
    *(float4*)(op + 4) = o1;
}

extern "C" void kernel_launch(void* const* d_in, const int* in_sizes, int n_in,
                              void* d_out, int out_size, void* d_ws, size_t ws_size,
                              hipStream_t stream) {
    const float* x     = (const float*)d_in[0];
    const int*   ei    = (const int*)d_in[1];
    const float* W     = (const float*)d_in[2];
    const float* att_i = (const float*)d_in[3];
    const float* att_j = (const float*)d_in[4];
    float* out = (float*)d_out;

    char* ws = (char*)d_ws;
    size_t off = 0;
    auto alloc = [&](size_t bytes) {
        void* p = ws + off;
        off += (bytes + 255) & ~(size_t)255;
        return p;
    };
    ushort* hb      = (ushort*)alloc((size_t)N_NODES * OUT_ALL * 2);   // 12.8 MB
    float*  ai      = (float*)alloc((size_t)N_NODES * HEADS * 4);      // 1.6 MB
    float*  aj      = (float*)alloc((size_t)N_NODES * HEADS * 4);      // 1.6 MB
    float*  wiwj    = (float*)alloc((size_t)IN_F * 8 * 4);             // 4 KB
    int*    scursor = (int*)alloc((size_t)NSLICES * 4);                // 1.6 KB
    int2*   seg     = (int2*)alloc((size_t)NSLICES * SEG_CAP * 8);     // 14.4 MB

    prep_kernel<<<(IN_F * 8 + 255) / 256, 256, 0, stream>>>(
        W, att_i, att_j, wiwj, scursor);
    proj_bin_kernel<<<TOTAL_BLOCKS, 256, 0, stream>>>(
        x, W, wiwj, ei, hb, ai, aj, scursor, seg);
    agg_kernel<<<NSLICES * 4, 512, 0, stream>>>(seg, scursor, hb, ai, aj, out);
}

// Round 14
// 96.100 us; speedup vs baseline: 8.2860x; 1.1336x over previous
//
#include <hip/hip_runtime.h>

typedef __attribute__((ext_vector_type(8))) short short8;
typedef __attribute__((ext_vector_type(4))) float f32x4;

#define N_NODES 100000
#define N_EDGES 1600000
#define IN_F 128
#define OUT_ALL 64   // HEADS*OUT_F
#define HEADS 4
#define OUT_F 16
#define NTILES (N_NODES / 16)          // 6250
#define BIN_BLOCKS 250
#define EPB (N_EDGES / BIN_BLOCKS)     // 6400 edges per bin block
#define TOTAL_BLOCKS 2048
#define PROJ_BLOCKS (TOTAL_BLOCKS - BIN_BLOCKS)   // 1798
#define SLICE_SHIFT 8
#define SLICE_NODES 256
#define NSLICES ((N_NODES + SLICE_NODES - 1) / SLICE_NODES)   // 391
#define SEG_CAP 4608                   // avg 4096 + 8 sigma
#define QUARTER_NODES 64
#define SORT_CAP 1280                  // quarter: avg 1024 + 8 sigma

static __device__ __forceinline__ ushort f2bf(float f) {
    unsigned u = __float_as_uint(f);
    return (ushort)((u + 0x7FFF + ((u >> 16) & 1)) >> 16);   // RN, no NaN inputs
}
static __device__ __forceinline__ float bf2f(ushort b) {
    return __uint_as_float(((unsigned)b) << 16);
}
static __device__ __forceinline__ short8 pack_bf16x8(float4 f0, float4 f1) {
    union { unsigned u[4]; short8 s; } r;
    asm("v_cvt_pk_bf16_f32 %0, %1, %2" : "=v"(r.u[0]) : "v"(f0.x), "v"(f0.y));
    asm("v_cvt_pk_bf16_f32 %0, %1, %2" : "=v"(r.u[1]) : "v"(f0.z), "v"(f0.w));
    asm("v_cvt_pk_bf16_f32 %0, %1, %2" : "=v"(r.u[2]) : "v"(f1.x), "v"(f1.y));
    asm("v_cvt_pk_bf16_f32 %0, %1, %2" : "=v"(r.u[3]) : "v"(f1.z), "v"(f1.w));
    return r.s;
}

// ---- Kernel 0: fold att into W + zero scursor ----------------------------
__global__ __launch_bounds__(256) void prep_kernel(
    const float* __restrict__ W, const float* __restrict__ att_i,
    const float* __restrict__ att_j, float* __restrict__ wiwj,
    int* __restrict__ scursor)
{
    int idx = blockIdx.x * 256 + threadIdx.x;
    if (idx < NSLICES) scursor[idx] = 0;
    if (idx >= IN_F * 8) return;
    int k = idx >> 3, c = idx & 7;
    int h = c & 3;
    const float* att = (c < 4) ? att_i : att_j;
    float s = 0.f;
    #pragma unroll
    for (int f = 0; f < 16; ++f)
        s += W[(size_t)(h * 16 + f) * IN_F + k] * att[h * OUT_F + f];
    wiwj[k * 8 + c] = s;
}

// ---- Kernel 1: fused MFMA projection (LDS-staged x) + slice binning ------
// Proj role: stage the 16x128 x-tile ONCE per block into LDS (coalesced
// float4), all 4 waves (heads) build A-frags from LDS — removes the 4x
// redundant scattered global loads that R13 counters identified.
// Bin role: unchanged from R13.
__global__ __launch_bounds__(256) void proj_bin_kernel(
    const float* __restrict__ x, const float* __restrict__ W,
    const float* __restrict__ wiwj, const int* __restrict__ ei,
    ushort* __restrict__ hb, float* __restrict__ ai, float* __restrict__ aj,
    int* __restrict__ scursor, int2* __restrict__ seg)
{
    __shared__ int cnt[NSLICES];              // 1.6 KB
    __shared__ int gbase[NSLICES];            // 1.6 KB
    __shared__ int run[NSLICES];              // 1.6 KB
    __shared__ float xs[16][129];             // 8.3 KB, +1 pad: ~2-way banks

    if (blockIdx.x < BIN_BLOCKS) {
        int base = blockIdx.x * EPB;
        const int4* __restrict__ srcp = (const int4*)(ei + base);
        const int4* __restrict__ dstp = (const int4*)(ei + N_EDGES + base);
        for (int s = threadIdx.x; s < NSLICES; s += 256) { cnt[s] = 0; run[s] = 0; }
        __syncthreads();
        for (int i = threadIdx.x; i < EPB / 4; i += 256) {
            int4 d = dstp[i];
            atomicAdd(&cnt[d.x >> SLICE_SHIFT], 1);
            atomicAdd(&cnt[d.y >> SLICE_SHIFT], 1);
            atomicAdd(&cnt[d.z >> SLICE_SHIFT], 1);
            atomicAdd(&cnt[d.w >> SLICE_SHIFT], 1);
        }
        __syncthreads();
        for (int s = threadIdx.x; s < NSLICES; s += 256) {
            int c = cnt[s];
            gbase[s] = c ? atomicAdd(&scursor[s], c) : 0;
        }
        __syncthreads();
        for (int i = threadIdx.x; i < EPB / 4; i += 256) {
            int4 sv = srcp[i];
            int4 dv = dstp[i];
            int ss, p;
            ss = dv.x >> SLICE_SHIFT; p = gbase[ss] + atomicAdd(&run[ss], 1);
            if (p < SEG_CAP) seg[(size_t)ss * SEG_CAP + p] = make_int2(sv.x, dv.x);
            ss = dv.y >> SLICE_SHIFT; p = gbase[ss] + atomicAdd(&run[ss], 1);
            if (p < SEG_CAP) seg[(size_t)ss * SEG_CAP + p] = make_int2(sv.y, dv.y);
            ss = dv.z >> SLICE_SHIFT; p = gbase[ss] + atomicAdd(&run[ss], 1);
            if (p < SEG_CAP) seg[(size_t)ss * SEG_CAP + p] = make_int2(sv.z, dv.z);
            ss = dv.w >> SLICE_SHIFT; p = gbase[ss] + atomicAdd(&run[ss], 1);
            if (p < SEG_CAP) seg[(size_t)ss * SEG_CAP + p] = make_int2(sv.w, dv.w);
        }
        return;
    }

    int bproj = blockIdx.x - BIN_BLOCKS;       // 0..1797
    const int nproj = PROJ_BLOCKS;

    int w   = threadIdx.x >> 6;    // wave id == head == 16-col n-tile
    int l   = threadIdx.x & 63;
    int col = l & 15;
    int kg  = l >> 4;              // k-group 0..3 (8 k each)

    // B-frags: rows of W (f32 -> bf16), one per 32-wide K block
    short8 bw[4];
    #pragma unroll
    for (int m = 0; m < 4; ++m) {
        const float* wp = W + (size_t)(w * 16 + col) * IN_F + m * 32 + kg * 8;
        float4 f0 = *(const float4*)wp;
        float4 f1 = *(const float4*)(wp + 4);
        bw[m] = pack_bf16x8(f0, f1);
    }
    // B-frags for the att-dot MFMA: cols 0..7 = wiwj, cols 8..15 = 0
    short8 bwd[4];
    #pragma unroll
    for (int m = 0; m < 4; ++m) {
        float v[8];
        #pragma unroll
        for (int j = 0; j < 8; ++j)
            v[j] = (col < 8) ? wiwj[(size_t)(m * 32 + kg * 8 + j) * 8 + col] : 0.f;
        bwd[m] = pack_bf16x8(float4{v[0], v[1], v[2], v[3]},
                             float4{v[4], v[5], v[6], v[7]});
    }

    for (int t = bproj; t < NTILES; t += nproj) {
        int nodeBase = t * 16;

        __syncthreads();   // protect xs from previous-iteration readers
        // stage 16x128 f32 tile, coalesced: 512 float4 chunks over 256 thr
        #pragma unroll
        for (int r = 0; r < 2; ++r) {
            int chunk = threadIdx.x + r * 256;     // 0..511
            int row = chunk >> 5, c4 = chunk & 31;
            float4 v = *(const float4*)(x + (size_t)(nodeBase + row) * IN_F + c4 * 4);
            xs[row][c4 * 4 + 0] = v.x;
            xs[row][c4 * 4 + 1] = v.y;
            xs[row][c4 * 4 + 2] = v.z;
            xs[row][c4 * 4 + 3] = v.w;
        }
        __syncthreads();

        // A-frags from LDS (scalar reads, ~2-way banks), convert once/wave
        short8 a[4];
        #pragma unroll
        for (int m = 0; m < 4; ++m) {
            const float* xr = &xs[col][m * 32 + kg * 8];
            float4 f0 = {xr[0], xr[1], xr[2], xr[3]};
            float4 f1 = {xr[4], xr[5], xr[6], xr[7]};
            a[m] = pack_bf16x8(f0, f1);
        }
        f32x4 acc = {0.f, 0.f, 0.f, 0.f};
        f32x4 accd = {0.f, 0.f, 0.f, 0.f};
        #pragma unroll
        for (int m = 0; m < 4; ++m) {
            acc  = __builtin_amdgcn_mfma_f32_16x16x32_bf16(a[m], bw[m],  acc,  0, 0, 0);
            accd = __builtin_amdgcn_mfma_f32_16x16x32_bf16(a[m], bwd[m], accd, 0, 0, 0);
        }

        #pragma unroll
        for (int r = 0; r < 4; ++r)
            hb[(size_t)(nodeBase + kg * 4 + r) * OUT_ALL + w * 16 + col] = f2bf(acc[r]);

        if (col < 4) {
            #pragma unroll
            for (int r = 0; r < 4; ++r)
                ai[(size_t)(nodeBase + kg * 4 + r) * HEADS + col] = accd[r];
        } else if (col < 8) {
            #pragma unroll
            for (int r = 0; r < 4; ++r)
                aj[(size_t)(nodeBase + kg * 4 + r) * HEADS + (col - 4)] = accd[r];
        }
    }
}

// ---- Kernel 2: quarter-slice counting-sort + register gather (unchanged) -
__global__ __launch_bounds__(512) void agg_kernel(
    const int2* __restrict__ seg, const int* __restrict__ scursor,
    const ushort* __restrict__ hb, const float* __restrict__ ai,
    const float* __restrict__ aj, float* __restrict__ out)
{
    __shared__ int sorted_src[SORT_CAP];      // 5.1 KB
    __shared__ int cnt[QUARTER_NODES];
    __shared__ int run[QUARTER_NODES];
    __shared__ int rowptr[QUARTER_NODES + 1];

    int s       = blockIdx.x >> 2;
    int quarter = blockIdx.x & 3;
    int nbase   = (s << SLICE_SHIFT) + quarter * QUARTER_NODES;
    int total = scursor[s]; if (total > SEG_CAP) total = SEG_CAP;
    const int2* sp = seg + (size_t)s * SEG_CAP;

    for (int i = threadIdx.x; i < QUARTER_NODES; i += 512) { cnt[i] = 0; run[i] = 0; }
    __syncthreads();

    for (int i = threadIdx.x; i < total; i += 512) {
        int d = sp[i].y & (SLICE_NODES - 1);
        if ((d >> 6) == quarter) atomicAdd(&cnt[d & (QUARTER_NODES - 1)], 1);
    }
    __syncthreads();

    if (threadIdx.x < 64) {
        int l = threadIdx.x;
        int v = cnt[l];
        int inc = v;
        #pragma unroll
        for (int d = 1; d < 64; d <<= 1) {
            int t = __shfl_up(inc, d, 64);
            if (l >= d) inc += t;
        }
        rowptr[l] = inc - v;
        if (l == 63) rowptr[64] = inc;
    }
    __syncthreads();

    for (int i = threadIdx.x; i < total; i += 512) {
        int2 e = sp[i];
        int d = e.y & (SLICE_NODES - 1);
        if ((d >> 6) == quarter) {
            int lb = d & (QUARTER_NODES - 1);
            int p = rowptr[lb] + atomicAdd(&run[lb], 1);
            if (p < SORT_CAP) sorted_src[p] = e.x;
        }
    }
    __syncthreads();

    int g    = threadIdx.x >> 3;   // 0..63 == local node
    int sub  = threadIdx.x & 7;    // 8 lanes, 8 cols each
    int head = sub >> 1;
    int node = nbase + g;
    if (node >= N_NODES) return;
    int beg = rowptr[g], end = rowptr[g + 1];
    if (end > SORT_CAP) end = SORT_CAP;
    float aiv = ai[(size_t)node * HEADS + head];
    float acc[8] = {0.f, 0.f, 0.f, 0.f, 0.f, 0.f, 0.f, 0.f};
    float den = 0.f;
    for (int k = beg; k < end; ++k) {
        int src = sorted_src[k];               // LDS broadcast to 8 lanes
        float av = aiv + aj[(size_t)src * HEADS + head];
        av = av > 0.f ? av : 0.01f * av;
        float ex = __expf(av);
        den += ex;
        short8 hv = *(const short8*)(hb + (size_t)src * OUT_ALL + sub * 8);
        #pragma unroll
        for (int q = 0; q < 8; ++q)
            acc[q] += ex * bf2f((ushort)hv[q]);
    }
    float inv = 1.0f / (den + 1e-16f);
    float4 o0 = {acc[0] * inv, acc[1] * inv, acc[2] * inv, acc[3] * inv};
    float4 o1 = {acc[4] * inv, acc[5] * inv, acc[6] * inv, acc[7] * inv};
    float* op = out + (size_t)node * OUT_ALL + sub * 8;
    *(float4*)op = o0;
    *(float4*)(op + 4) = o1;
}

extern "C" void kernel_launch(void* const* d_in, const int* in_sizes, int n_in,
                              void* d_out, int out_size, void* d_ws, size_t ws_size,
                              hipStream_t stream) {
    const float* x     = (const float*)d_in[0];
    const int*   ei    = (const int*)d_in[1];
    const float* W     = (const float*)d_in[2];
    const float* att_i = (const float*)d_in[3];
    const float* att_j = (const float*)d_in[4];
    float* out = (float*)d_out;

    char* ws = (char*)d_ws;
    size_t off = 0;
    auto alloc = [&](size_t bytes) {
        void* p = ws + off;
        off += (bytes + 255) & ~(size_t)255;
        return p;
    };
    ushort* hb      = (ushort*)alloc((size_t)N_NODES * OUT_ALL * 2);   // 12.8 MB
    float*  ai      = (float*)alloc((size_t)N_NODES * HEADS * 4);      // 1.6 MB
    float*  aj      = (float*)alloc((size_t)N_NODES * HEADS * 4);      // 1.6 MB
    float*  wiwj    = (float*)alloc((size_t)IN_F * 8 * 4);             // 4 KB
    int*    scursor = (int*)alloc((size_t)NSLICES * 4);                // 1.6 KB
    int2*   seg     = (int2*)alloc((size_t)NSLICES * SEG_CAP * 8);     // 14.4 MB

    prep_kernel<<<(IN_F * 8 + 255) / 256, 256, 0, stream>>>(
        W, att_i, att_j, wiwj, scursor);
    proj_bin_kernel<<<TOTAL_BLOCKS, 256, 0, stream>>>(
        x, W, wiwj, ei, hb, ai, aj, scursor, seg);
    agg_kernel<<<NSLICES * 4, 512, 0, stream>>>(seg, scursor, hb, ai, aj, out);
}